// Round 4
// baseline (758.897 us; speedup 1.0000x reference)
//
#include <hip/hip_runtime.h>

#define Bsz 512
#define Lsz 512
#define Tsz 128
#define TAG_START 126
#define TAG_STOP 127
#define SPB 16            // sequences per block (= MFMA N)
#define UPITCH 138        // u_lds row pitch in bf16 elems (128 + 10). 138*2B=276B=69
                          // words, 69%32=5 odd -> b128 row-reads spread 5s mod 32,
                          // near-conflict-free (vs 136: 68%32=4 -> 8-way aliasing)

typedef __attribute__((ext_vector_type(8))) short short8;   // 8 bf16 = MFMA A/B frag
typedef __attribute__((ext_vector_type(4))) float f32x4;    // MFMA C/D frag

__device__ __forceinline__ unsigned pack_bf16(float lo, float hi) {
  unsigned a = (__float_as_uint(lo) + 0x8000u) >> 16;
  unsigned b = (__float_as_uint(hi) + 0x8000u) & 0xFFFF0000u;
  return b | a;
}
__device__ __forceinline__ float bf16lo(unsigned d) { return __uint_as_float(d << 16); }
__device__ __forceinline__ float bf16hi(unsigned d) { return __uint_as_float(d & 0xFFFF0000u); }

// ONE WAVE PER BLOCK (64 threads), 32 blocks -> one wave per CU, private LDS.
// The wave owns all 16 seqs and all 8 M-tiles: 32 mfma_16x16x32 per step sharing
// 4 B-frags. u(t)->u(t+1) is a same-wave LDS write->read ordered by lgkmcnt(0);
// NO s_barrier, NO cross-wave exchange, NO helpers. Emit ring is per-seq
// lim-clamped (Round-2 pattern) so FETCH stays ~36MB (Round 3's 2x fetch bug
// was the unclamped helper produce()). __launch_bounds__(64,1) -> up to 512
// VGPRs: af[8][4] (128) + 2-deep ring (64) stay resident.
// Numerics: op-for-op identical to the verified kernels (same pack rounding,
// same (acc*rce)*ee association, same eta-from-packed-word, Round-3's verified
// terminal tree, Round-2's gold lane pattern) -> absmax 0.0 expected.
__global__ __launch_bounds__(64, 1) void crf_fwd_kernel(
    const float* __restrict__ feats, const float* __restrict__ trans,
    const int* __restrict__ tags, const int* __restrict__ lens,
    float* __restrict__ diff_out)
{
  __shared__ __align__(16) unsigned short u_lds[2][SPB][UPITCH];   // ~8.8 KB
  __shared__ float gold_sh[SPB];

  const int g    = blockIdx.x;
  const int lane = threadIdx.x;   // 0..63 (single wave)
  const int q    = lane >> 4;     // quad
  const int s    = lane & 15;     // column: seq-in-block / MFMA n
  const int seq  = g * SPB + s;
  const int lenc = lens[seq];
  const int lim  = lenc - 1;

  // block maxlen: shuffle-reduce within 16-lane groups (all 4 groups identical)
  int maxlen = lenc;
  #pragma unroll
  for (int off = 1; off < 16; off <<= 1) {
    int o = __shfl_xor(maxlen, off, 64);
    maxlen = o > maxlen ? o : maxlen;
  }

  for (int i = lane; i < 2 * SPB * UPITCH; i += 64)
    ((unsigned short*)u_lds)[i] = 0;
  __syncthreads();                         // 1 wave: cheap, orders init
  if (lane < SPB) u_lds[0][lane][TAG_START] = 0x3F80;   // bf16 1.0
  __syncthreads();

  // A-frags: af[i][c] elem j = exp(trans[i*16+s][32c+8q+j]) bf16 (verbatim)
  short8 af[8][4];
  float ucap[8][4];
  #pragma unroll
  for (int i = 0; i < 8; ++i) {
    const float* tr = trans + (size_t)(i * 16 + s) * Tsz + q * 8;
    #pragma unroll
    for (int c = 0; c < 4; ++c) {
      float4 x = *(const float4*)(tr + c * 32);
      float4 y = *(const float4*)(tr + c * 32 + 4);
      union { unsigned u[4]; short8 v; } cv;
      cv.u[0] = pack_bf16(__expf(x.x), __expf(x.y));
      cv.u[1] = pack_bf16(__expf(x.z), __expf(x.w));
      cv.u[2] = pack_bf16(__expf(y.x), __expf(y.y));
      cv.u[3] = pack_bf16(__expf(y.z), __expf(y.w));
      af[i][c] = cv.v;
    }
    ucap[i][0] = ucap[i][1] = ucap[i][2] = ucap[i][3] = 1.0f;
  }

  // Emit base: lane's 32 C-rows = {16i+4q+r}, col = seq s.
  const float* fp = feats + (size_t)seq * (Lsz * Tsz) + 4 * q;

  // 2-deep lim-clamped ring: ra = step t (even), rb = step t+1 (odd)
  float4 ra[8], rb[8];
  { int r1 = (1 < lim) ? 1 : lim;          // min(1, lim), lim >= 0
    #pragma unroll
    for (int i = 0; i < 8; ++i) {
      ra[i] = *(const float4*)(fp + 16 * i);
      rb[i] = *(const float4*)(fp + (size_t)r1 * Tsz + 16 * i);
    } }

  float m_run = 0.0f, mcap = 0.0f;

#define STEP(T, RBUF, WBUF, CUR)                                               \
  { const int t_ = (T);                                                        \
    /* exps for this step (trans pipe, overlaps MFMA) */                       \
    float4 eex[8];                                                             \
    _Pragma("unroll") for (int i = 0; i < 8; ++i) {                            \
      eex[i].x = __expf(CUR[i].x); eex[i].y = __expf(CUR[i].y);                \
      eex[i].z = __expf(CUR[i].z); eex[i].w = __expf(CUR[i].w);                \
    }                                                                          \
    /* prefetch t+2 into the slot just consumed (lim-clamped) */               \
    { int tp = t_ + 2; tp = (tp < lim) ? tp : lim;                             \
      _Pragma("unroll") for (int i = 0; i < 8; ++i)                            \
        CUR[i] = *(const float4*)(fp + (size_t)tp * Tsz + 16 * i); }           \
    /* full-u B-frags for col s, shared by all 8 tiles */                      \
    const unsigned short* ub = &u_lds[RBUF][s][0];                             \
    short8 bq0 = *(const short8*)(ub + 0 * 32 + q * 8);                        \
    short8 bq1 = *(const short8*)(ub + 1 * 32 + q * 8);                        \
    short8 bq2 = *(const short8*)(ub + 2 * 32 + q * 8);                        \
    short8 bq3 = *(const short8*)(ub + 3 * 32 + q * 8);                        \
    unsigned ud = *(const unsigned*)ub;                                        \
    f32x4 acc[8];                                                              \
    _Pragma("unroll") for (int i = 0; i < 8; ++i) {                            \
      f32x4 a = {0.f, 0.f, 0.f, 0.f};                                          \
      a = __builtin_amdgcn_mfma_f32_16x16x32_bf16(af[i][0], bq0, a, 0, 0, 0);  \
      a = __builtin_amdgcn_mfma_f32_16x16x32_bf16(af[i][1], bq1, a, 0, 0, 0);  \
      a = __builtin_amdgcn_mfma_f32_16x16x32_bf16(af[i][2], bq2, a, 0, 0, 0);  \
      a = __builtin_amdgcn_mfma_f32_16x16x32_bf16(af[i][3], bq3, a, 0, 0, 0);  \
      acc[i] = a;                                                              \
    }                                                                          \
    float eta = bf16lo(ud) + bf16hi(ud);                                       \
    if (t_ == 0) eta = 1.0f;                                                   \
    float rce = __builtin_amdgcn_rcpf(eta);                                    \
    bool capt = (t_ == lim);                                                   \
    float uv[8][4];                                                            \
    _Pragma("unroll") for (int i = 0; i < 8; ++i) {                            \
      uv[i][0] = acc[i][0] * rce * eex[i].x;                                   \
      uv[i][1] = acc[i][1] * rce * eex[i].y;                                   \
      uv[i][2] = acc[i][2] * rce * eex[i].z;                                   \
      uv[i][3] = acc[i][3] * rce * eex[i].w;                                   \
    }                                                                          \
    m_run += __logf(eta);                                                      \
    if (capt) {                                                                \
      _Pragma("unroll") for (int i = 0; i < 8; ++i) {                          \
        ucap[i][0] = uv[i][0]; ucap[i][1] = uv[i][1];                          \
        ucap[i][2] = uv[i][2]; ucap[i][3] = uv[i][3];                          \
      }                                                                        \
      mcap = m_run;                                                            \
    }                                                                          \
    unsigned short* dst = &u_lds[WBUF][s][0];                                  \
    _Pragma("unroll") for (int i = 0; i < 8; ++i) {                            \
      uint2 pk;                                                                \
      pk.x = pack_bf16(uv[i][0], uv[i][1]);                                    \
      pk.y = pack_bf16(uv[i][2], uv[i][3]);                                    \
      *(uint2*)(dst + 16 * i + 4 * q) = pk;                                    \
    }                                                                          \
    /* same-wave write->read ordering; no barrier (single wave) */             \
    asm volatile("s_waitcnt lgkmcnt(0)" ::: "memory");                         \
  }

  for (int t = 0; t < maxlen; t += 2) {
    STEP(t + 0, 0, 1, ra)
    STEP(t + 1, 1, 0, rb)
  }
#undef STEP

  // ---- terminal logsumexp (Round-3's verified tree, verbatim) ----
  float fwd_score;
  {
    float fvv[8][4];
    const float* tr2 = trans + TAG_START * Tsz + 4 * q;
    #pragma unroll
    for (int i = 0; i < 8; ++i) {
      float4 tv = *(const float4*)(tr2 + 16 * i);
      fvv[i][0] = __logf(ucap[i][0]) + mcap + tv.x;
      fvv[i][1] = __logf(ucap[i][1]) + mcap + tv.y;
      fvv[i][2] = __logf(ucap[i][2]) + mcap + tv.z;
      fvv[i][3] = __logf(ucap[i][3]) + mcap + tv.w;
    }
    float redm[4], reds[4];
    #pragma unroll
    for (int w2 = 0; w2 < 4; ++w2) {
      float mx = fvv[2 * w2][0];
      mx = fmaxf(mx, fvv[2 * w2][1]);
      mx = fmaxf(mx, fvv[2 * w2][2]);
      mx = fmaxf(mx, fvv[2 * w2][3]);
      mx = fmaxf(mx, fvv[2 * w2 + 1][0]);
      mx = fmaxf(mx, fvv[2 * w2 + 1][1]);
      mx = fmaxf(mx, fvv[2 * w2 + 1][2]);
      mx = fmaxf(mx, fvv[2 * w2 + 1][3]);
      mx = fmaxf(mx, __shfl_xor(mx, 16, 64));
      mx = fmaxf(mx, __shfl_xor(mx, 32, 64));
      redm[w2] = mx;
    }
    float gmx = fmaxf(fmaxf(redm[0], redm[1]), fmaxf(redm[2], redm[3]));
    #pragma unroll
    for (int w2 = 0; w2 < 4; ++w2) {
      float se = 0.f;
      #pragma unroll
      for (int r = 0; r < 4; ++r) se += __expf(fvv[2 * w2][r] - gmx);
      #pragma unroll
      for (int r = 0; r < 4; ++r) se += __expf(fvv[2 * w2 + 1][r] - gmx);
      se += __shfl_xor(se, 16, 64);
      se += __shfl_xor(se, 32, 64);
      reds[w2] = se;
    }
    fwd_score = gmx + __logf((reds[0] + reds[1]) + (reds[2] + reds[3]));
  }

  // ---- gold score: 4 passes, seq jj = 4*it+q, 16 lanes (s) per seq ----
  #pragma unroll
  for (int it = 0; it < 4; ++it) {
    int jj = 4 * it + q;
    int gs2 = g * SPB + jj;
    int lenj = lens[gs2];
    const int* tg = tags + (size_t)gs2 * Lsz;
    const float* fbj = feats + (size_t)gs2 * (Lsz * Tsz);
    float gacc = 0.f;
    for (int pos = s; pos <= lenj; pos += 16) {
      int st = (pos == 0)    ? TAG_START : tg[pos - 1];
      int et = (pos == lenj) ? TAG_STOP  : tg[pos];
      gacc += trans[et * Tsz + st];
    }
    for (int l = s; l < lenj; l += 16)
      gacc += fbj[(size_t)l * Tsz + tg[l]];
    #pragma unroll
    for (int off = 1; off < 16; off <<= 1) gacc += __shfl_xor(gacc, off, 64);
    if (s == 0) gold_sh[jj] = gacc;
  }
  __syncthreads();
  if (q == 0)
    diff_out[g * SPB + s] = fwd_score - gold_sh[s];
}

// loss = mean(diff)
__global__ __launch_bounds__(Bsz) void crf_final_kernel(
    const float* __restrict__ diff, float* __restrict__ out)
{
  int tid = threadIdx.x;
  float v = diff[tid];
  __shared__ float wred[8];
  float sum = v;
  #pragma unroll
  for (int off = 32; off > 0; off >>= 1) sum += __shfl_down(sum, off, 64);
  int wave = tid >> 6, lane = tid & 63;
  if (lane == 0) wred[wave] = sum;
  __syncthreads();
  if (tid == 0) {
    float t = 0.f;
    #pragma unroll
    for (int i = 0; i < 8; ++i) t += wred[i];
    out[0] = t * (1.0f / Bsz);
  }
}

extern "C" void kernel_launch(void* const* d_in, const int* in_sizes, int n_in,
                              void* d_out, int out_size, void* d_ws, size_t ws_size,
                              hipStream_t stream) {
  const float* feats = (const float*)d_in[0];
  const float* trans = (const float*)d_in[1];
  const int*   tags  = (const int*)d_in[2];
  const int*   lens  = (const int*)d_in[3];
  float* out  = (float*)d_out;
  float* diff = (float*)d_ws;

  crf_fwd_kernel<<<Bsz / SPB, 64, 0, stream>>>(feats, trans, tags, lens, diff);
  crf_final_kernel<<<1, Bsz, 0, stream>>>(diff, out);
}

// Round 5
// 463.486 us; speedup vs baseline: 1.6374x; 1.6374x over previous
//
#include <hip/hip_runtime.h>

#define Bsz 512
#define Lsz 512
#define Tsz 128
#define TAG_START 126
#define TAG_STOP 127
#define SPB 16            // sequences per block
#define UPITCH 138        // u_lds row pitch in bf16 elems (128 + 10 pad).
                          // 138*2B = 276B = 69 words; 69 odd -> row starts spread
                          // 5*s mod 32 (16 distinct banks for s=0..15). Round-4
                          // measured ZERO SQ_LDS_BANK_CONFLICT with this pitch vs
                          // 2.7M at 136 (68 words -> 4s mod 32, s/s+8 alias).

typedef __attribute__((ext_vector_type(8))) short short8;   // 8 bf16 = MFMA A/B frag
typedef __attribute__((ext_vector_type(4))) float f32x4;    // MFMA C/D frag

// Barrier draining ONLY LDS (lgkmcnt) - global prefetch loads stay in flight.
__device__ __forceinline__ void lds_barrier() {
  asm volatile("s_waitcnt lgkmcnt(0)\n\ts_barrier" ::: "memory");
}
__device__ __forceinline__ unsigned pack_bf16(float lo, float hi) {
  unsigned a = (__float_as_uint(lo) + 0x8000u) >> 16;
  unsigned b = (__float_as_uint(hi) + 0x8000u) & 0xFFFF0000u;
  return b | a;
}
__device__ __forceinline__ float bf16lo(unsigned d) { return __uint_as_float(d << 16); }
__device__ __forceinline__ float bf16hi(unsigned d) { return __uint_as_float(d & 0xFFFF0000u); }

// One block = 16 sequences, 512 threads = 8 waves; wave w owns M-tile w (16 rows).
// Per step per wave: P(16x16) = expT_tile(16x128) . U(128x16), ONE 4-deep MFMA chain.
// This is the verified Round-2 kernel (250us fwd) with ONE change: UPITCH 136->138
// to kill the ~165 cy/step LDS bank-conflict serialization (hw-verified at 0
// conflicts in Round 4's probe). Numerics bit-identical to Round 2.
__global__ __launch_bounds__(512) void crf_fwd_kernel(
    const float* __restrict__ feats, const float* __restrict__ trans,
    const int* __restrict__ tags, const int* __restrict__ lens,
    float* __restrict__ diff_out)
{
  __shared__ __align__(16) unsigned short u_lds[2][SPB][UPITCH];
  __shared__ float fv_sh[Tsz][SPB];     // one-time terminal staging (8 KB)
  __shared__ float red[4][SPB];
  __shared__ float gold_sh[SPB];
  __shared__ int msh;

  const int g    = blockIdx.x;
  const int tid  = threadIdx.x;
  const int w    = tid >> 6;      // wave 0..7: owns M-tile w
  const int lane = tid & 63;
  const int q    = lane >> 4;     // quad
  const int s    = lane & 15;     // column: seq-in-block / MFMA n / A-row m
  const int seq  = g * SPB + s;
  const int lenc = lens[seq];
  const int lim  = lenc - 1;

  if (tid == 0) msh = 1;
  __syncthreads();
  if (tid < SPB) atomicMax(&msh, lens[g * SPB + tid]);
  for (int i = tid; i < 2 * SPB * UPITCH; i += 512)
    ((unsigned short*)u_lds)[i] = 0;
  __syncthreads();
  const int maxlen = msh;
  if (tid < SPB) u_lds[0][tid][TAG_START] = 0x3F80;   // bf16 1.0
  __syncthreads();

  // A-frag: af[c] = exp(trans[w*16+s][32c+8q+j]) bf16
  short8 af[4];
  {
    const float* tr = trans + (size_t)(w * 16 + s) * Tsz + q * 8;
    #pragma unroll
    for (int c = 0; c < 4; ++c) {
      float4 x = *(const float4*)(tr + c * 32);
      float4 y = *(const float4*)(tr + c * 32 + 4);
      union { unsigned u[4]; short8 v; } cv;
      cv.u[0] = pack_bf16(__expf(x.x), __expf(x.y));
      cv.u[1] = pack_bf16(__expf(x.z), __expf(x.w));
      cv.u[2] = pack_bf16(__expf(y.x), __expf(y.y));
      cv.u[3] = pack_bf16(__expf(y.z), __expf(y.w));
      af[c] = cv.v;
    }
  }

  // Emit pointer: lane's 4 C-entries = rows w*16+4q+[0..4), col s.
  const float* fp = feats + (size_t)seq * (Lsz * Tsz) + w * 16 + 4 * q;

  // 4-deep static ring: slot k holds emit row (t with t%4==k), clamped to lim
  float4 pa0, pa1, pa2, pa3;
  { int r1 = (1 < lim) ? 1 : lim, r2 = (2 < lim) ? 2 : lim, r3 = (3 < lim) ? 3 : lim;
    if (lim < 1) r1 = r2 = r3 = lim;
    pa0 = *(const float4*)(fp);
    pa1 = *(const float4*)(fp + ((size_t)r1 << 7));
    pa2 = *(const float4*)(fp + ((size_t)r2 << 7));
    pa3 = *(const float4*)(fp + ((size_t)r3 << 7)); }

  float ee[4] = {__expf(pa0.x), __expf(pa0.y), __expf(pa0.z), __expf(pa0.w)};

  float m_run = 0.0f, mcap = 0.0f;
  float ucap[4];
  #pragma unroll
  for (int i = 0; i < 4; ++i) ucap[i] = 1.0f;

#define STEP(T, PA, NA, BR, BW)                                                \
  { const int t_ = (T);                                                        \
    short8 bq0 = *(const short8*)&u_lds[BR][s][0 * 32 + q * 8];                \
    short8 bq1 = *(const short8*)&u_lds[BR][s][1 * 32 + q * 8];                \
    short8 bq2 = *(const short8*)&u_lds[BR][s][2 * 32 + q * 8];                \
    short8 bq3 = *(const short8*)&u_lds[BR][s][3 * 32 + q * 8];                \
    unsigned ud = *(const unsigned*)&u_lds[BR][s][0];                          \
    int tp = t_ + 4; tp = (tp < lim) ? tp : lim;                               \
    PA = *(const float4*)(fp + ((size_t)tp << 7));                             \
    f32x4 acc = {0.f, 0.f, 0.f, 0.f};                                          \
    acc = __builtin_amdgcn_mfma_f32_16x16x32_bf16(af[0], bq0, acc, 0,0,0);     \
    acc = __builtin_amdgcn_mfma_f32_16x16x32_bf16(af[1], bq1, acc, 0,0,0);     \
    acc = __builtin_amdgcn_mfma_f32_16x16x32_bf16(af[2], bq2, acc, 0,0,0);     \
    acc = __builtin_amdgcn_mfma_f32_16x16x32_bf16(af[3], bq3, acc, 0,0,0);     \
    float eta = bf16lo(ud) + bf16hi(ud);                                       \
    if (t_ == 0) eta = 1.0f;                                                   \
    float rce = __builtin_amdgcn_rcpf(eta);                                    \
    bool capt = (t_ == lim);                                                   \
    float uv[4];                                                               \
    _Pragma("unroll") for (int i = 0; i < 4; ++i)                              \
      uv[i] = acc[i] * rce * ee[i];                                            \
    _Pragma("unroll") for (int i = 0; i < 4; ++i)                              \
      ucap[i] = capt ? uv[i] : ucap[i];                                        \
    m_run += __logf(eta);                                                      \
    mcap = capt ? m_run : mcap;                                                \
    unsigned short* dst = &u_lds[BW][s][0];                                    \
    uint2 pk; pk.x = pack_bf16(uv[0], uv[1]); pk.y = pack_bf16(uv[2], uv[3]);  \
    *(uint2*)&dst[w * 16 + 4 * q] = pk;                                        \
    ee[0] = __expf(NA.x); ee[1] = __expf(NA.y);                                \
    ee[2] = __expf(NA.z); ee[3] = __expf(NA.w);                                \
    lds_barrier();                                                             \
  }

  for (int t = 0; t < maxlen; t += 4) {
    STEP(t + 0, pa0, pa1, 0, 1)
    STEP(t + 1, pa1, pa2, 1, 0)
    STEP(t + 2, pa2, pa3, 0, 1)
    STEP(t + 3, pa3, pa0, 1, 0)
  }
#undef STEP

  __syncthreads();

  // Terminal fv: each wave computes its own 4 rows (bit-identical per element),
  // stages to LDS; waves 0-3 then replay the EXACT old 8-value reduction tree.
  #pragma unroll
  for (int r = 0; r < 4; ++r) {
    int row = w * 16 + 4 * q + r;
    fv_sh[row][s] = __logf(ucap[r]) + mcap + trans[TAG_START * Tsz + row];
  }
  __syncthreads();

  float fwd_score = 0.f;
  float fvv[8];
  if (w < 4) {
    #pragma unroll
    for (int i = 0; i < 2; ++i)
      #pragma unroll
      for (int r = 0; r < 4; ++r)
        fvv[i * 4 + r] = fv_sh[(2 * w + i) * 16 + 4 * q + r][s];
    float mx = fvv[0];
    #pragma unroll
    for (int i = 1; i < 8; ++i) mx = fmaxf(mx, fvv[i]);
    mx = fmaxf(mx, __shfl_xor(mx, 16, 64));
    mx = fmaxf(mx, __shfl_xor(mx, 32, 64));
    if (q == 0) red[w][s] = mx;
  }
  __syncthreads();
  float gmx = 0.f;
  if (w < 4) gmx = fmaxf(fmaxf(red[0][s], red[1][s]), fmaxf(red[2][s], red[3][s]));
  __syncthreads();
  if (w < 4) {
    float se = 0.f;
    #pragma unroll
    for (int i = 0; i < 8; ++i) se += __expf(fvv[i] - gmx);
    se += __shfl_xor(se, 16, 64);
    se += __shfl_xor(se, 32, 64);
    if (q == 0) red[w][s] = se;
  }
  __syncthreads();
  if (w < 4)
    fwd_score = gmx + __logf((red[0][s] + red[1][s]) + (red[2][s] + red[3][s]));

  // ---- gold score: waves 0-3 exactly as before (seq 4w+q; 16 lanes per seq) ----
  if (w < 4) {
    int jj = 4 * w + q;
    int gs2 = g * SPB + jj;
    int lenj = lens[gs2];
    const int* tg = tags + (size_t)gs2 * Lsz;
    const float* fbj = feats + (size_t)gs2 * (Lsz * Tsz);
    float acc = 0.f;
    for (int pos = s; pos <= lenj; pos += 16) {
      int st = (pos == 0)    ? TAG_START : tg[pos - 1];
      int et = (pos == lenj) ? TAG_STOP  : tg[pos];
      acc += trans[et * Tsz + st];
    }
    for (int l = s; l < lenj; l += 16)
      acc += fbj[(size_t)l * Tsz + tg[l]];
    #pragma unroll
    for (int off = 1; off < 16; off <<= 1) acc += __shfl_xor(acc, off, 64);
    if (s == 0) gold_sh[jj] = acc;
  }
  __syncthreads();
  if (w == 0 && q == 0)
    diff_out[g * SPB + s] = fwd_score - gold_sh[s];
}

// loss = mean(diff)
__global__ __launch_bounds__(Bsz) void crf_final_kernel(
    const float* __restrict__ diff, float* __restrict__ out)
{
  int tid = threadIdx.x;
  float v = diff[tid];
  __shared__ float wred[8];
  float sum = v;
  #pragma unroll
  for (int off = 32; off > 0; off >>= 1) sum += __shfl_down(sum, off, 64);
  int wave = tid >> 6, lane = tid & 63;
  if (lane == 0) wred[wave] = sum;
  __syncthreads();
  if (tid == 0) {
    float t = 0.f;
    #pragma unroll
    for (int i = 0; i < 8; ++i) t += wred[i];
    out[0] = t * (1.0f / Bsz);
  }
}

extern "C" void kernel_launch(void* const* d_in, const int* in_sizes, int n_in,
                              void* d_out, int out_size, void* d_ws, size_t ws_size,
                              hipStream_t stream) {
  const float* feats = (const float*)d_in[0];
  const float* trans = (const float*)d_in[1];
  const int*   tags  = (const int*)d_in[2];
  const int*   lens  = (const int*)d_in[3];
  float* out  = (float*)d_out;
  float* diff = (float*)d_ws;

  crf_fwd_kernel<<<Bsz / SPB, 512, 0, stream>>>(feats, trans, tags, lens, diff);
  crf_final_kernel<<<1, Bsz, 0, stream>>>(diff, out);
}

// Round 6
// 454.965 us; speedup vs baseline: 1.6680x; 1.0187x over previous
//
#include <hip/hip_runtime.h>

#define Bsz 512
#define Lsz 512
#define Tsz 128
#define TAG_START 126
#define TAG_STOP 127
#define SPB 16            // sequences per block
#define UPITCH 136        // u_lds row pitch in bf16 elems (128 + 8 pad).
                          // MUST be multiple of 8 (16B row alignment) or the
                          // short8 reads split (R5 regression: 138 -> 312us).

typedef __attribute__((ext_vector_type(8))) short short8;   // 8 bf16 = MFMA A/B frag
typedef __attribute__((ext_vector_type(4))) float f32x4;    // MFMA C/D frag

// Barrier draining ONLY LDS (lgkmcnt) - global prefetch loads stay in flight.
__device__ __forceinline__ void lds_barrier() {
  asm volatile("s_waitcnt lgkmcnt(0)\n\ts_barrier" ::: "memory");
}
__device__ __forceinline__ unsigned pack_bf16(float lo, float hi) {
  unsigned a = (__float_as_uint(lo) + 0x8000u) >> 16;
  unsigned b = (__float_as_uint(hi) + 0x8000u) & 0xFFFF0000u;
  return b | a;
}
__device__ __forceinline__ float bf16lo(unsigned d) { return __uint_as_float(d << 16); }
__device__ __forceinline__ float bf16hi(unsigned d) { return __uint_as_float(d & 0xFFFF0000u); }

// One block = 16 sequences, 128 threads = 2 WAVES; wave w owns 4 M-tiles
// (tiles 4w..4w+3, rows w*64..w*64+63). Rationale (R2..R5 evidence):
//  - total LDS read traffic per step = 4 b128 * W (each wave re-reads full u);
//    W=8 (R2) -> 384+ cy LDS pipe/step. W=2 -> 96 cy.
//  - W=1 (R4) spills (af needs 128 VGPR). W=2: af[4][4]=64 VGPR, ~210 total.
//  - barrier syncs only 2 waves -> minimal skew.
// STEP arithmetic is verbatim R2/R4 (same pack rounding, same (acc*rce)*ee,
// same eta-from-packed-word, per-seq lim-clamped ring) -> absmax 0.0 expected.
__global__ __launch_bounds__(128, 1) void crf_fwd_kernel(
    const float* __restrict__ feats, const float* __restrict__ trans,
    const int* __restrict__ tags, const int* __restrict__ lens,
    float* __restrict__ diff_out)
{
  __shared__ __align__(16) unsigned short u_lds[2][SPB][UPITCH];
  __shared__ float fv_sh[Tsz][SPB];     // one-time terminal staging (8 KB)
  __shared__ float gold_sh[SPB];
  __shared__ int msh;

  const int g    = blockIdx.x;
  const int tid  = threadIdx.x;
  const int w    = tid >> 6;      // wave 0..1: owns tiles 4w..4w+3
  const int lane = tid & 63;
  const int q    = lane >> 4;     // quad
  const int s    = lane & 15;     // column: seq-in-block / MFMA n
  const int seq  = g * SPB + s;
  const int lenc = lens[seq];
  const int lim  = lenc - 1;

  if (tid == 0) msh = 1;
  __syncthreads();
  if (tid < SPB) atomicMax(&msh, lens[g * SPB + tid]);
  for (int i = tid; i < 2 * SPB * UPITCH; i += 128)
    ((unsigned short*)u_lds)[i] = 0;
  __syncthreads();
  const int maxlen = msh;
  if (tid < SPB) u_lds[0][tid][TAG_START] = 0x3F80;   // bf16 1.0
  __syncthreads();

  // A-frags: af[i][c] elem j = exp(trans[(4w+i)*16+s][32c+8q+j]) bf16 (verbatim)
  short8 af[4][4];
  float ucap[4][4];
  #pragma unroll
  for (int i = 0; i < 4; ++i) {
    const float* tr = trans + (size_t)((4 * w + i) * 16 + s) * Tsz + q * 8;
    #pragma unroll
    for (int c = 0; c < 4; ++c) {
      float4 x = *(const float4*)(tr + c * 32);
      float4 y = *(const float4*)(tr + c * 32 + 4);
      union { unsigned u[4]; short8 v; } cv;
      cv.u[0] = pack_bf16(__expf(x.x), __expf(x.y));
      cv.u[1] = pack_bf16(__expf(x.z), __expf(x.w));
      cv.u[2] = pack_bf16(__expf(y.x), __expf(y.y));
      cv.u[3] = pack_bf16(__expf(y.z), __expf(y.w));
      af[i][c] = cv.v;
    }
    ucap[i][0] = ucap[i][1] = ucap[i][2] = ucap[i][3] = 1.0f;
  }

  // Emit base: lane's 16 C-rows = {(4w+i)*16+4q+r}, col = seq s.
  const float* fp = feats + (size_t)seq * (Lsz * Tsz) + w * 64 + 4 * q;

  // 2-deep lim-clamped ring (R4-verified): ra = even steps, rb = odd steps
  float4 ra[4], rb[4];
  { int r1 = (1 < lim) ? 1 : lim;          // min(1, lim), lim >= 0
    #pragma unroll
    for (int i = 0; i < 4; ++i) {
      ra[i] = *(const float4*)(fp + 16 * i);
      rb[i] = *(const float4*)(fp + (size_t)r1 * Tsz + 16 * i);
    } }

  float m_run = 0.0f, mcap = 0.0f;

#define STEP(T, RBUF, WBUF, CUR)                                               \
  { const int t_ = (T);                                                        \
    float4 eex[4];                                                             \
    _Pragma("unroll") for (int i = 0; i < 4; ++i) {                            \
      eex[i].x = __expf(CUR[i].x); eex[i].y = __expf(CUR[i].y);                \
      eex[i].z = __expf(CUR[i].z); eex[i].w = __expf(CUR[i].w);                \
    }                                                                          \
    { int tp = t_ + 2; tp = (tp < lim) ? tp : lim;                             \
      _Pragma("unroll") for (int i = 0; i < 4; ++i)                            \
        CUR[i] = *(const float4*)(fp + (size_t)tp * Tsz + 16 * i); }           \
    const unsigned short* ub = &u_lds[RBUF][s][0];                             \
    short8 bq0 = *(const short8*)(ub + 0 * 32 + q * 8);                        \
    short8 bq1 = *(const short8*)(ub + 1 * 32 + q * 8);                        \
    short8 bq2 = *(const short8*)(ub + 2 * 32 + q * 8);                        \
    short8 bq3 = *(const short8*)(ub + 3 * 32 + q * 8);                        \
    unsigned ud = *(const unsigned*)ub;                                        \
    f32x4 acc[4];                                                              \
    _Pragma("unroll") for (int i = 0; i < 4; ++i) {                            \
      f32x4 a = {0.f, 0.f, 0.f, 0.f};                                          \
      a = __builtin_amdgcn_mfma_f32_16x16x32_bf16(af[i][0], bq0, a, 0, 0, 0);  \
      a = __builtin_amdgcn_mfma_f32_16x16x32_bf16(af[i][1], bq1, a, 0, 0, 0);  \
      a = __builtin_amdgcn_mfma_f32_16x16x32_bf16(af[i][2], bq2, a, 0, 0, 0);  \
      a = __builtin_amdgcn_mfma_f32_16x16x32_bf16(af[i][3], bq3, a, 0, 0, 0);  \
      acc[i] = a;                                                              \
    }                                                                          \
    float eta = bf16lo(ud) + bf16hi(ud);                                       \
    if (t_ == 0) eta = 1.0f;                                                   \
    float rce = __builtin_amdgcn_rcpf(eta);                                    \
    bool capt = (t_ == lim);                                                   \
    float uv[4][4];                                                            \
    _Pragma("unroll") for (int i = 0; i < 4; ++i) {                            \
      uv[i][0] = acc[i][0] * rce * eex[i].x;                                   \
      uv[i][1] = acc[i][1] * rce * eex[i].y;                                   \
      uv[i][2] = acc[i][2] * rce * eex[i].z;                                   \
      uv[i][3] = acc[i][3] * rce * eex[i].w;                                   \
    }                                                                          \
    m_run += __logf(eta);                                                      \
    if (capt) {                                                                \
      _Pragma("unroll") for (int i = 0; i < 4; ++i) {                          \
        ucap[i][0] = uv[i][0]; ucap[i][1] = uv[i][1];                          \
        ucap[i][2] = uv[i][2]; ucap[i][3] = uv[i][3];                          \
      }                                                                        \
      mcap = m_run;                                                            \
    }                                                                          \
    unsigned short* dst = &u_lds[WBUF][s][0];                                  \
    _Pragma("unroll") for (int i = 0; i < 4; ++i) {                            \
      uint2 pk;                                                                \
      pk.x = pack_bf16(uv[i][0], uv[i][1]);                                    \
      pk.y = pack_bf16(uv[i][2], uv[i][3]);                                    \
      *(uint2*)(dst + (4 * w + i) * 16 + 4 * q) = pk;                          \
    }                                                                          \
    lds_barrier();                                                             \
  }

  for (int t = 0; t < maxlen; t += 2) {
    STEP(t + 0, 0, 1, ra)
    STEP(t + 1, 1, 0, rb)
  }
#undef STEP

  __syncthreads();

  // Terminal fv: stage own rows (bit-identical per element), then wave 0
  // replays the EXACT verified reduction tree (R2 staging + R3 replay).
  #pragma unroll
  for (int i = 0; i < 4; ++i)
    #pragma unroll
    for (int r = 0; r < 4; ++r) {
      int row = (4 * w + i) * 16 + 4 * q + r;
      fv_sh[row][s] = __logf(ucap[i][r]) + mcap + trans[TAG_START * Tsz + row];
    }
  __syncthreads();

  float fwd_score = 0.f;
  if (w == 0) {
    float fvv[4][8];
    float redm[4], reds[4];
    #pragma unroll
    for (int w2 = 0; w2 < 4; ++w2) {
      #pragma unroll
      for (int i = 0; i < 2; ++i)
        #pragma unroll
        for (int r = 0; r < 4; ++r)
          fvv[w2][i * 4 + r] = fv_sh[(2 * w2 + i) * 16 + 4 * q + r][s];
      float mx = fvv[w2][0];
      #pragma unroll
      for (int i = 1; i < 8; ++i) mx = fmaxf(mx, fvv[w2][i]);
      mx = fmaxf(mx, __shfl_xor(mx, 16, 64));
      mx = fmaxf(mx, __shfl_xor(mx, 32, 64));
      redm[w2] = mx;
    }
    float gmx = fmaxf(fmaxf(redm[0], redm[1]), fmaxf(redm[2], redm[3]));
    #pragma unroll
    for (int w2 = 0; w2 < 4; ++w2) {
      float se = 0.f;
      #pragma unroll
      for (int i = 0; i < 8; ++i) se += __expf(fvv[w2][i] - gmx);
      se += __shfl_xor(se, 16, 64);
      se += __shfl_xor(se, 32, 64);
      reds[w2] = se;
    }
    fwd_score = gmx + __logf((reds[0] + reds[1]) + (reds[2] + reds[3]));
  }

  // ---- gold score: 2 passes/wave, seq jj = 8*it + 4*w + q (same 16-lane
  // per-seq pattern as every verified version) ----
  #pragma unroll
  for (int it = 0; it < 2; ++it) {
    int jj = 8 * it + 4 * w + q;
    int gs2 = g * SPB + jj;
    int lenj = lens[gs2];
    const int* tg = tags + (size_t)gs2 * Lsz;
    const float* fbj = feats + (size_t)gs2 * (Lsz * Tsz);
    float gacc = 0.f;
    for (int pos = s; pos <= lenj; pos += 16) {
      int st = (pos == 0)    ? TAG_START : tg[pos - 1];
      int et = (pos == lenj) ? TAG_STOP  : tg[pos];
      gacc += trans[et * Tsz + st];
    }
    for (int l = s; l < lenj; l += 16)
      gacc += fbj[(size_t)l * Tsz + tg[l]];
    #pragma unroll
    for (int off = 1; off < 16; off <<= 1) gacc += __shfl_xor(gacc, off, 64);
    if (s == 0) gold_sh[jj] = gacc;
  }
  __syncthreads();
  if (w == 0 && q == 0)
    diff_out[g * SPB + s] = fwd_score - gold_sh[s];
}

// loss = mean(diff)
__global__ __launch_bounds__(Bsz) void crf_final_kernel(
    const float* __restrict__ diff, float* __restrict__ out)
{
  int tid = threadIdx.x;
  float v = diff[tid];
  __shared__ float wred[8];
  float sum = v;
  #pragma unroll
  for (int off = 32; off > 0; off >>= 1) sum += __shfl_down(sum, off, 64);
  int wave = tid >> 6, lane = tid & 63;
  if (lane == 0) wred[wave] = sum;
  __syncthreads();
  if (tid == 0) {
    float t = 0.f;
    #pragma unroll
    for (int i = 0; i < 8; ++i) t += wred[i];
    out[0] = t * (1.0f / Bsz);
  }
}

extern "C" void kernel_launch(void* const* d_in, const int* in_sizes, int n_in,
                              void* d_out, int out_size, void* d_ws, size_t ws_size,
                              hipStream_t stream) {
  const float* feats = (const float*)d_in[0];
  const float* trans = (const float*)d_in[1];
  const int*   tags  = (const int*)d_in[2];
  const int*   lens  = (const int*)d_in[3];
  float* out  = (float*)d_out;
  float* diff = (float*)d_ws;

  crf_fwd_kernel<<<Bsz / SPB, 128, 0, stream>>>(feats, trans, tags, lens, diff);
  crf_final_kernel<<<1, Bsz, 0, stream>>>(diff, out);
}

// Round 7
// 401.770 us; speedup vs baseline: 1.8889x; 1.1324x over previous
//
#include <hip/hip_runtime.h>

#define Bsz 512
#define Lsz 512
#define Tsz 128
#define TAG_START 126
#define TAG_STOP 127
#define SPB 16            // sequences per block
#define UPITCH 136        // u_lds row pitch in bf16 elems (128 + 8 pad).
                          // MUST be multiple of 8 (16B row alignment) or the
                          // short8 reads split (R5 regression: 138 -> 312us).

typedef __attribute__((ext_vector_type(8))) short short8;   // 8 bf16 = MFMA A/B frag
typedef __attribute__((ext_vector_type(4))) float f32x4;    // MFMA C/D frag

// Barrier draining ONLY LDS (lgkmcnt) - global prefetch loads stay in flight.
__device__ __forceinline__ void lds_barrier() {
  asm volatile("s_waitcnt lgkmcnt(0)\n\ts_barrier" ::: "memory");
}
__device__ __forceinline__ unsigned pack_bf16(float lo, float hi) {
  unsigned a = (__float_as_uint(lo) + 0x8000u) >> 16;
  unsigned b = (__float_as_uint(hi) + 0x8000u) & 0xFFFF0000u;
  return b | a;
}
__device__ __forceinline__ float bf16lo(unsigned d) { return __uint_as_float(d << 16); }
__device__ __forceinline__ float bf16hi(unsigned d) { return __uint_as_float(d & 0xFFFF0000u); }

// One block = 16 sequences, 512 threads = 8 waves; wave w owns M-tile w (16 rows).
// This is the verified Round-2 kernel (250us fwd, absmax 0.0) with ONE change:
// the 4 emit exps are computed at the TOP of STEP (inside the ~150cy ds_read
// latency shadow) instead of at the bottom (between LDS write and barrier, the
// tightest serial segment of the ~1060cy step skeleton). Values are identical
// (same ring slot, read before the t+4 prefetch overwrites it) -> absmax 0.0.
__global__ __launch_bounds__(512) void crf_fwd_kernel(
    const float* __restrict__ feats, const float* __restrict__ trans,
    const int* __restrict__ tags, const int* __restrict__ lens,
    float* __restrict__ diff_out)
{
  __shared__ __align__(16) unsigned short u_lds[2][SPB][UPITCH];
  __shared__ float fv_sh[Tsz][SPB];     // one-time terminal staging (8 KB)
  __shared__ float red[4][SPB];
  __shared__ float gold_sh[SPB];
  __shared__ int msh;

  const int g    = blockIdx.x;
  const int tid  = threadIdx.x;
  const int w    = tid >> 6;      // wave 0..7: owns M-tile w
  const int lane = tid & 63;
  const int q    = lane >> 4;     // quad
  const int s    = lane & 15;     // column: seq-in-block / MFMA n / A-row m
  const int seq  = g * SPB + s;
  const int lenc = lens[seq];
  const int lim  = lenc - 1;

  if (tid == 0) msh = 1;
  __syncthreads();
  if (tid < SPB) atomicMax(&msh, lens[g * SPB + tid]);
  for (int i = tid; i < 2 * SPB * UPITCH; i += 512)
    ((unsigned short*)u_lds)[i] = 0;
  __syncthreads();
  const int maxlen = msh;
  if (tid < SPB) u_lds[0][tid][TAG_START] = 0x3F80;   // bf16 1.0
  __syncthreads();

  // A-frag: af[c] = exp(trans[w*16+s][32c+8q+j]) bf16
  short8 af[4];
  {
    const float* tr = trans + (size_t)(w * 16 + s) * Tsz + q * 8;
    #pragma unroll
    for (int c = 0; c < 4; ++c) {
      float4 x = *(const float4*)(tr + c * 32);
      float4 y = *(const float4*)(tr + c * 32 + 4);
      union { unsigned u[4]; short8 v; } cv;
      cv.u[0] = pack_bf16(__expf(x.x), __expf(x.y));
      cv.u[1] = pack_bf16(__expf(x.z), __expf(x.w));
      cv.u[2] = pack_bf16(__expf(y.x), __expf(y.y));
      cv.u[3] = pack_bf16(__expf(y.z), __expf(y.w));
      af[c] = cv.v;
    }
  }

  // Emit pointer: lane's 4 C-entries = rows w*16+4q+[0..4), col s.
  const float* fp = feats + (size_t)seq * (Lsz * Tsz) + w * 16 + 4 * q;

  // 4-deep static ring: slot k holds emit row (t with t%4==k), clamped to lim
  float4 pa0, pa1, pa2, pa3;
  { int r1 = (1 < lim) ? 1 : lim, r2 = (2 < lim) ? 2 : lim, r3 = (3 < lim) ? 3 : lim;
    if (lim < 1) r1 = r2 = r3 = lim;
    pa0 = *(const float4*)(fp);
    pa1 = *(const float4*)(fp + ((size_t)r1 << 7));
    pa2 = *(const float4*)(fp + ((size_t)r2 << 7));
    pa3 = *(const float4*)(fp + ((size_t)r3 << 7)); }

  float m_run = 0.0f, mcap = 0.0f;
  float ucap[4];
  #pragma unroll
  for (int i = 0; i < 4; ++i) ucap[i] = 1.0f;

// eex computed at TOP from this step's slot (before the t+4 prefetch
// overwrites it) -> exps issue during ds_read latency, not before barrier.
#define STEP(T, PA, BR, BW)                                                    \
  { const int t_ = (T);                                                        \
    float eex0 = __expf(PA.x), eex1 = __expf(PA.y);                            \
    float eex2 = __expf(PA.z), eex3 = __expf(PA.w);                            \
    short8 bq0 = *(const short8*)&u_lds[BR][s][0 * 32 + q * 8];                \
    short8 bq1 = *(const short8*)&u_lds[BR][s][1 * 32 + q * 8];                \
    short8 bq2 = *(const short8*)&u_lds[BR][s][2 * 32 + q * 8];                \
    short8 bq3 = *(const short8*)&u_lds[BR][s][3 * 32 + q * 8];                \
    unsigned ud = *(const unsigned*)&u_lds[BR][s][0];                          \
    int tp = t_ + 4; tp = (tp < lim) ? tp : lim;                               \
    PA = *(const float4*)(fp + ((size_t)tp << 7));                             \
    f32x4 acc = {0.f, 0.f, 0.f, 0.f};                                          \
    acc = __builtin_amdgcn_mfma_f32_16x16x32_bf16(af[0], bq0, acc, 0,0,0);     \
    acc = __builtin_amdgcn_mfma_f32_16x16x32_bf16(af[1], bq1, acc, 0,0,0);     \
    acc = __builtin_amdgcn_mfma_f32_16x16x32_bf16(af[2], bq2, acc, 0,0,0);     \
    acc = __builtin_amdgcn_mfma_f32_16x16x32_bf16(af[3], bq3, acc, 0,0,0);     \
    float eta = bf16lo(ud) + bf16hi(ud);                                       \
    if (t_ == 0) eta = 1.0f;                                                   \
    float rce = __builtin_amdgcn_rcpf(eta);                                    \
    bool capt = (t_ == lim);                                                   \
    float uv[4];                                                               \
    uv[0] = acc[0] * rce * eex0;                                               \
    uv[1] = acc[1] * rce * eex1;                                               \
    uv[2] = acc[2] * rce * eex2;                                               \
    uv[3] = acc[3] * rce * eex3;                                               \
    _Pragma("unroll") for (int i = 0; i < 4; ++i)                              \
      ucap[i] = capt ? uv[i] : ucap[i];                                        \
    m_run += __logf(eta);                                                      \
    mcap = capt ? m_run : mcap;                                                \
    unsigned short* dst = &u_lds[BW][s][0];                                    \
    uint2 pk; pk.x = pack_bf16(uv[0], uv[1]); pk.y = pack_bf16(uv[2], uv[3]);  \
    *(uint2*)&dst[w * 16 + 4 * q] = pk;                                        \
    lds_barrier();                                                             \
  }

  for (int t = 0; t < maxlen; t += 4) {
    STEP(t + 0, pa0, 0, 1)
    STEP(t + 1, pa1, 1, 0)
    STEP(t + 2, pa2, 0, 1)
    STEP(t + 3, pa3, 1, 0)
  }
#undef STEP

  __syncthreads();

  // Terminal fv: each wave computes its own 4 rows (bit-identical per element),
  // stages to LDS; waves 0-3 then replay the EXACT old 8-value reduction tree.
  #pragma unroll
  for (int r = 0; r < 4; ++r) {
    int row = w * 16 + 4 * q + r;
    fv_sh[row][s] = __logf(ucap[r]) + mcap + trans[TAG_START * Tsz + row];
  }
  __syncthreads();

  float fwd_score = 0.f;
  float fvv[8];
  if (w < 4) {
    #pragma unroll
    for (int i = 0; i < 2; ++i)
      #pragma unroll
      for (int r = 0; r < 4; ++r)
        fvv[i * 4 + r] = fv_sh[(2 * w + i) * 16 + 4 * q + r][s];
    float mx = fvv[0];
    #pragma unroll
    for (int i = 1; i < 8; ++i) mx = fmaxf(mx, fvv[i]);
    mx = fmaxf(mx, __shfl_xor(mx, 16, 64));
    mx = fmaxf(mx, __shfl_xor(mx, 32, 64));
    if (q == 0) red[w][s] = mx;
  }
  __syncthreads();
  float gmx = 0.f;
  if (w < 4) gmx = fmaxf(fmaxf(red[0][s], red[1][s]), fmaxf(red[2][s], red[3][s]));
  __syncthreads();
  if (w < 4) {
    float se = 0.f;
    #pragma unroll
    for (int i = 0; i < 8; ++i) se += __expf(fvv[i] - gmx);
    se += __shfl_xor(se, 16, 64);
    se += __shfl_xor(se, 32, 64);
    if (q == 0) red[w][s] = se;
  }
  __syncthreads();
  if (w < 4)
    fwd_score = gmx + __logf((red[0][s] + red[1][s]) + (red[2][s] + red[3][s]));

  // ---- gold score: waves 0-3 exactly as before (seq 4w+q; 16 lanes per seq) ----
  if (w < 4) {
    int jj = 4 * w + q;
    int gs2 = g * SPB + jj;
    int lenj = lens[gs2];
    const int* tg = tags + (size_t)gs2 * Lsz;
    const float* fbj = feats + (size_t)gs2 * (Lsz * Tsz);
    float acc = 0.f;
    for (int pos = s; pos <= lenj; pos += 16) {
      int st = (pos == 0)    ? TAG_START : tg[pos - 1];
      int et = (pos == lenj) ? TAG_STOP  : tg[pos];
      acc += trans[et * Tsz + st];
    }
    for (int l = s; l < lenj; l += 16)
      acc += fbj[(size_t)l * Tsz + tg[l]];
    #pragma unroll
    for (int off = 1; off < 16; off <<= 1) acc += __shfl_xor(acc, off, 64);
    if (s == 0) gold_sh[jj] = acc;
  }
  __syncthreads();
  if (w == 0 && q == 0)
    diff_out[g * SPB + s] = fwd_score - gold_sh[s];
}

// loss = mean(diff)
__global__ __launch_bounds__(Bsz) void crf_final_kernel(
    const float* __restrict__ diff, float* __restrict__ out)
{
  int tid = threadIdx.x;
  float v = diff[tid];
  __shared__ float wred[8];
  float sum = v;
  #pragma unroll
  for (int off = 32; off > 0; off >>= 1) sum += __shfl_down(sum, off, 64);
  int wave = tid >> 6, lane = tid & 63;
  if (lane == 0) wred[wave] = sum;
  __syncthreads();
  if (tid == 0) {
    float t = 0.f;
    #pragma unroll
    for (int i = 0; i < 8; ++i) t += wred[i];
    out[0] = t * (1.0f / Bsz);
  }
}

extern "C" void kernel_launch(void* const* d_in, const int* in_sizes, int n_in,
                              void* d_out, int out_size, void* d_ws, size_t ws_size,
                              hipStream_t stream) {
  const float* feats = (const float*)d_in[0];
  const float* trans = (const float*)d_in[1];
  const int*   tags  = (const int*)d_in[2];
  const int*   lens  = (const int*)d_in[3];
  float* out  = (float*)d_out;
  float* diff = (float*)d_ws;

  crf_fwd_kernel<<<Bsz / SPB, 512, 0, stream>>>(feats, trans, tags, lens, diff);
  crf_final_kernel<<<1, Bsz, 0, stream>>>(diff, out);
}

// Round 9
// 396.460 us; speedup vs baseline: 1.9142x; 1.0134x over previous
//
#include <hip/hip_runtime.h>

#define Bsz 512
#define Lsz 512
#define Tsz 128
#define TAG_START 126
#define TAG_STOP 127
#define SPB 16            // sequences per block
#define UPITCH 136        // u_lds row pitch in bf16 elems (128 + 8 pad).
                          // MUST be multiple of 8 (16B row alignment) or the
                          // short8 reads split (R5 regression: 138 -> 312us).

typedef __attribute__((ext_vector_type(8))) short short8;   // 8 bf16 = MFMA A/B frag
typedef __attribute__((ext_vector_type(4))) float f32x4;    // MFMA C/D frag

// Barrier draining ONLY LDS (lgkmcnt) - global prefetch loads stay in flight.
__device__ __forceinline__ void lds_barrier() {
  asm volatile("s_waitcnt lgkmcnt(0)\n\ts_barrier" ::: "memory");
}
__device__ __forceinline__ unsigned pack_bf16(float lo, float hi) {
  unsigned a = (__float_as_uint(lo) + 0x8000u) >> 16;
  unsigned b = (__float_as_uint(hi) + 0x8000u) & 0xFFFF0000u;
  return b | a;
}
__device__ __forceinline__ float bf16lo(unsigned d) { return __uint_as_float(d << 16); }
__device__ __forceinline__ float bf16hi(unsigned d) { return __uint_as_float(d & 0xFFFF0000u); }

// One block = 16 sequences, 512 threads = 8 waves; wave w owns M-tile w (16 rows).
// R7 base (248us fwd) with two chain cuts (R8's ud-from-bq0 REVERTED - it read
// u[s][q*8] instead of u[s][0] for q!=0, absmax 192):
//  1. MFMA dep chain split 4 -> 2+2 parallel + f32x4 add: halves the serial
//     matrix-pipe latency on the u(t)->u(t+1) critical path. (Reassociates the
//     f32 accumulator at the ~ulp level - far below the bf16 output threshold.)
//  2. ucap/m_run bookkeeping moved AFTER the barrier (registers only) - the
//     pre-barrier serial segment ends at the ds_write.
__global__ __launch_bounds__(512) void crf_fwd_kernel(
    const float* __restrict__ feats, const float* __restrict__ trans,
    const int* __restrict__ tags, const int* __restrict__ lens,
    float* __restrict__ diff_out)
{
  __shared__ __align__(16) unsigned short u_lds[2][SPB][UPITCH];
  __shared__ float fv_sh[Tsz][SPB];     // one-time terminal staging (8 KB)
  __shared__ float red[4][SPB];
  __shared__ float gold_sh[SPB];
  __shared__ int msh;

  const int g    = blockIdx.x;
  const int tid  = threadIdx.x;
  const int w    = tid >> 6;      // wave 0..7: owns M-tile w
  const int lane = tid & 63;
  const int q    = lane >> 4;     // quad
  const int s    = lane & 15;     // column: seq-in-block / MFMA n / A-row m
  const int seq  = g * SPB + s;
  const int lenc = lens[seq];
  const int lim  = lenc - 1;

  if (tid == 0) msh = 1;
  __syncthreads();
  if (tid < SPB) atomicMax(&msh, lens[g * SPB + tid]);
  for (int i = tid; i < 2 * SPB * UPITCH; i += 512)
    ((unsigned short*)u_lds)[i] = 0;
  __syncthreads();
  const int maxlen = msh;
  if (tid < SPB) u_lds[0][tid][TAG_START] = 0x3F80;   // bf16 1.0
  __syncthreads();

  // A-frag: af[c] = exp(trans[w*16+s][32c+8q+j]) bf16
  short8 af[4];
  {
    const float* tr = trans + (size_t)(w * 16 + s) * Tsz + q * 8;
    #pragma unroll
    for (int c = 0; c < 4; ++c) {
      float4 x = *(const float4*)(tr + c * 32);
      float4 y = *(const float4*)(tr + c * 32 + 4);
      union { unsigned u[4]; short8 v; } cv;
      cv.u[0] = pack_bf16(__expf(x.x), __expf(x.y));
      cv.u[1] = pack_bf16(__expf(x.z), __expf(x.w));
      cv.u[2] = pack_bf16(__expf(y.x), __expf(y.y));
      cv.u[3] = pack_bf16(__expf(y.z), __expf(y.w));
      af[c] = cv.v;
    }
  }

  // Emit pointer: lane's 4 C-entries = rows w*16+4q+[0..4), col s.
  const float* fp = feats + (size_t)seq * (Lsz * Tsz) + w * 16 + 4 * q;

  // 4-deep static ring: slot k holds emit row (t with t%4==k), clamped to lim
  float4 pa0, pa1, pa2, pa3;
  { int r1 = (1 < lim) ? 1 : lim, r2 = (2 < lim) ? 2 : lim, r3 = (3 < lim) ? 3 : lim;
    if (lim < 1) r1 = r2 = r3 = lim;
    pa0 = *(const float4*)(fp);
    pa1 = *(const float4*)(fp + ((size_t)r1 << 7));
    pa2 = *(const float4*)(fp + ((size_t)r2 << 7));
    pa3 = *(const float4*)(fp + ((size_t)r3 << 7)); }

  float m_run = 0.0f, mcap = 0.0f;
  float ucap[4];
  #pragma unroll
  for (int i = 0; i < 4; ++i) ucap[i] = 1.0f;

// eex at top (R7, verified); ud via its own b32 read (correct for all quads);
// split MFMA chains; bookkeeping after barrier.
#define STEP(T, PA, BR, BW)                                                    \
  { const int t_ = (T);                                                        \
    float eex0 = __expf(PA.x), eex1 = __expf(PA.y);                            \
    float eex2 = __expf(PA.z), eex3 = __expf(PA.w);                            \
    short8 bq0 = *(const short8*)&u_lds[BR][s][0 * 32 + q * 8];                \
    short8 bq1 = *(const short8*)&u_lds[BR][s][1 * 32 + q * 8];                \
    short8 bq2 = *(const short8*)&u_lds[BR][s][2 * 32 + q * 8];                \
    short8 bq3 = *(const short8*)&u_lds[BR][s][3 * 32 + q * 8];                \
    unsigned ud = *(const unsigned*)&u_lds[BR][s][0];                          \
    int tp = t_ + 4; tp = (tp < lim) ? tp : lim;                               \
    PA = *(const float4*)(fp + ((size_t)tp << 7));                             \
    f32x4 z = {0.f, 0.f, 0.f, 0.f};                                            \
    f32x4 accA = __builtin_amdgcn_mfma_f32_16x16x32_bf16(af[0], bq0, z, 0,0,0);\
    f32x4 accB = __builtin_amdgcn_mfma_f32_16x16x32_bf16(af[2], bq2, z, 0,0,0);\
    accA = __builtin_amdgcn_mfma_f32_16x16x32_bf16(af[1], bq1, accA, 0,0,0);   \
    accB = __builtin_amdgcn_mfma_f32_16x16x32_bf16(af[3], bq3, accB, 0,0,0);   \
    float eta = bf16lo(ud) + bf16hi(ud);                                       \
    if (t_ == 0) eta = 1.0f;                                                   \
    float rce = __builtin_amdgcn_rcpf(eta);                                    \
    float uv[4];                                                               \
    uv[0] = (accA[0] + accB[0]) * rce * eex0;                                  \
    uv[1] = (accA[1] + accB[1]) * rce * eex1;                                  \
    uv[2] = (accA[2] + accB[2]) * rce * eex2;                                  \
    uv[3] = (accA[3] + accB[3]) * rce * eex3;                                  \
    unsigned short* dst = &u_lds[BW][s][0];                                    \
    uint2 pk; pk.x = pack_bf16(uv[0], uv[1]); pk.y = pack_bf16(uv[2], uv[3]);  \
    *(uint2*)&dst[w * 16 + 4 * q] = pk;                                        \
    lds_barrier();                                                             \
    bool capt = (t_ == lim);                                                   \
    _Pragma("unroll") for (int i = 0; i < 4; ++i)                              \
      ucap[i] = capt ? uv[i] : ucap[i];                                        \
    m_run += __logf(eta);                                                      \
    mcap = capt ? m_run : mcap;                                                \
  }

  for (int t = 0; t < maxlen; t += 4) {
    STEP(t + 0, pa0, 0, 1)
    STEP(t + 1, pa1, 1, 0)
    STEP(t + 2, pa2, 0, 1)
    STEP(t + 3, pa3, 1, 0)
  }
#undef STEP

  __syncthreads();

  // Terminal fv: each wave computes its own 4 rows, stages to LDS; waves 0-3
  // then replay the exact verified reduction tree.
  #pragma unroll
  for (int r = 0; r < 4; ++r) {
    int row = w * 16 + 4 * q + r;
    fv_sh[row][s] = __logf(ucap[r]) + mcap + trans[TAG_START * Tsz + row];
  }
  __syncthreads();

  float fwd_score = 0.f;
  float fvv[8];
  if (w < 4) {
    #pragma unroll
    for (int i = 0; i < 2; ++i)
      #pragma unroll
      for (int r = 0; r < 4; ++r)
        fvv[i * 4 + r] = fv_sh[(2 * w + i) * 16 + 4 * q + r][s];
    float mx = fvv[0];
    #pragma unroll
    for (int i = 1; i < 8; ++i) mx = fmaxf(mx, fvv[i]);
    mx = fmaxf(mx, __shfl_xor(mx, 16, 64));
    mx = fmaxf(mx, __shfl_xor(mx, 32, 64));
    if (q == 0) red[w][s] = mx;
  }
  __syncthreads();
  float gmx = 0.f;
  if (w < 4) gmx = fmaxf(fmaxf(red[0][s], red[1][s]), fmaxf(red[2][s], red[3][s]));
  __syncthreads();
  if (w < 4) {
    float se = 0.f;
    #pragma unroll
    for (int i = 0; i < 8; ++i) se += __expf(fvv[i] - gmx);
    se += __shfl_xor(se, 16, 64);
    se += __shfl_xor(se, 32, 64);
    if (q == 0) red[w][s] = se;
  }
  __syncthreads();
  if (w < 4)
    fwd_score = gmx + __logf((red[0][s] + red[1][s]) + (red[2][s] + red[3][s]));

  // ---- gold score: waves 0-3 exactly as before (seq 4w+q; 16 lanes per seq) ----
  if (w < 4) {
    int jj = 4 * w + q;
    int gs2 = g * SPB + jj;
    int lenj = lens[gs2];
    const int* tg = tags + (size_t)gs2 * Lsz;
    const float* fbj = feats + (size_t)gs2 * (Lsz * Tsz);
    float acc = 0.f;
    for (int pos = s; pos <= lenj; pos += 16) {
      int st = (pos == 0)    ? TAG_START : tg[pos - 1];
      int et = (pos == lenj) ? TAG_STOP  : tg[pos];
      acc += trans[et * Tsz + st];
    }
    for (int l = s; l < lenj; l += 16)
      acc += fbj[(size_t)l * Tsz + tg[l]];
    #pragma unroll
    for (int off = 1; off < 16; off <<= 1) acc += __shfl_xor(acc, off, 64);
    if (s == 0) gold_sh[jj] = acc;
  }
  __syncthreads();
  if (w == 0 && q == 0)
    diff_out[g * SPB + s] = fwd_score - gold_sh[s];
}

// loss = mean(diff)
__global__ __launch_bounds__(Bsz) void crf_final_kernel(
    const float* __restrict__ diff, float* __restrict__ out)
{
  int tid = threadIdx.x;
  float v = diff[tid];
  __shared__ float wred[8];
  float sum = v;
  #pragma unroll
  for (int off = 32; off > 0; off >>= 1) sum += __shfl_down(sum, off, 64);
  int wave = tid >> 6, lane = tid & 63;
  if (lane == 0) wred[wave] = sum;
  __syncthreads();
  if (tid == 0) {
    float t = 0.f;
    #pragma unroll
    for (int i = 0; i < 8; ++i) t += wred[i];
    out[0] = t * (1.0f / Bsz);
  }
}

extern "C" void kernel_launch(void* const* d_in, const int* in_sizes, int n_in,
                              void* d_out, int out_size, void* d_ws, size_t ws_size,
                              hipStream_t stream) {
  const float* feats = (const float*)d_in[0];
  const float* trans = (const float*)d_in[1];
  const int*   tags  = (const int*)d_in[2];
  const int*   lens  = (const int*)d_in[3];
  float* out  = (float*)d_out;
  float* diff = (float*)d_ws;

  crf_fwd_kernel<<<Bsz / SPB, 512, 0, stream>>>(feats, trans, tags, lens, diff);
  crf_final_kernel<<<1, Bsz, 0, stream>>>(diff, out);
}

// Round 10
// 379.366 us; speedup vs baseline: 2.0004x; 1.0451x over previous
//
#include <hip/hip_runtime.h>

#define Bsz 512
#define Lsz 512
#define Tsz 128
#define TAG_START 126
#define TAG_STOP 127
#define SPB 16            // sequences per block
#define UPITCH 136        // u_lds row pitch in bf16 elems (128 + 8 pad).
                          // MUST be multiple of 8 (16B row alignment) or the
                          // short8 reads split (R5 regression: 138 -> 312us).

typedef __attribute__((ext_vector_type(8))) short short8;   // 8 bf16 = MFMA A/B frag
typedef __attribute__((ext_vector_type(4))) float f32x4;    // MFMA C/D frag

// Barrier draining ONLY LDS (lgkmcnt) - global prefetch loads stay in flight.
__device__ __forceinline__ void lds_barrier() {
  asm volatile("s_waitcnt lgkmcnt(0)\n\ts_barrier" ::: "memory");
}
__device__ __forceinline__ unsigned pack_bf16(float lo, float hi) {
  unsigned a = (__float_as_uint(lo) + 0x8000u) >> 16;
  unsigned b = (__float_as_uint(hi) + 0x8000u) & 0xFFFF0000u;
  return b | a;
}
__device__ __forceinline__ float bf16lo(unsigned d) { return __uint_as_float(d << 16); }
__device__ __forceinline__ float bf16hi(unsigned d) { return __uint_as_float(d & 0xFFFF0000u); }
// RNE f32x2 -> packed bf16x2 in one instruction (no builtin on gfx950).
__device__ __forceinline__ unsigned cvt_pk_bf16(float lo, float hi) {
  unsigned r;
  asm("v_cvt_pk_bf16_f32 %0, %1, %2" : "=v"(r) : "v"(lo), "v"(hi));
  return r;
}

// One block = 16 sequences, 512 threads = 8 waves; wave w owns M-tile w (16 rows).
// R9 base (247us fwd, verified) + issue-volume cuts:
//  1. RESCALE EVERY 4th STEP ONLY. bf16 shares f32's exponent range (3.4e38);
//     worst-case per-step growth ~6e5, so 3 unrescaled steps peak ~2e17 - 21
//     orders of margin. eta==1 on the other steps: drops the eta b32 LDS read,
//     bf16 decode+add, rcp, __logf, and the rce multiplies from 3/4 of steps
//     (~40cy issue + ~20cy chain per wave). Invariant true_u = u*exp(m_run)
//     holds exactly at every step boundary; capture semantics unchanged.
//  2. v_cvt_pk_bf16_f32 pack (2 instrs) replaces manual round-half-up pack
//     (~10 instrs). RNE vs half-up differs only on exact ties (~ulp).
// Numerics: no longer bit-identical (different u quantization points), but
// bf16 relative precision is scale-invariant -> fwd_score perturbation ~0.1
// vs threshold 171.5.
__global__ __launch_bounds__(512) void crf_fwd_kernel(
    const float* __restrict__ feats, const float* __restrict__ trans,
    const int* __restrict__ tags, const int* __restrict__ lens,
    float* __restrict__ diff_out)
{
  __shared__ __align__(16) unsigned short u_lds[2][SPB][UPITCH];
  __shared__ float fv_sh[Tsz][SPB];     // one-time terminal staging (8 KB)
  __shared__ float red[4][SPB];
  __shared__ float gold_sh[SPB];
  __shared__ int msh;

  const int g    = blockIdx.x;
  const int tid  = threadIdx.x;
  const int w    = tid >> 6;      // wave 0..7: owns M-tile w
  const int lane = tid & 63;
  const int q    = lane >> 4;     // quad
  const int s    = lane & 15;     // column: seq-in-block / MFMA n / A-row m
  const int seq  = g * SPB + s;
  const int lenc = lens[seq];
  const int lim  = lenc - 1;

  if (tid == 0) msh = 1;
  __syncthreads();
  if (tid < SPB) atomicMax(&msh, lens[g * SPB + tid]);
  for (int i = tid; i < 2 * SPB * UPITCH; i += 512)
    ((unsigned short*)u_lds)[i] = 0;
  __syncthreads();
  const int maxlen = msh;
  if (tid < SPB) u_lds[0][tid][TAG_START] = 0x3F80;   // bf16 1.0
  __syncthreads();

  // A-frag: af[c] = exp(trans[w*16+s][32c+8q+j]) bf16
  short8 af[4];
  {
    const float* tr = trans + (size_t)(w * 16 + s) * Tsz + q * 8;
    #pragma unroll
    for (int c = 0; c < 4; ++c) {
      float4 x = *(const float4*)(tr + c * 32);
      float4 y = *(const float4*)(tr + c * 32 + 4);
      union { unsigned u[4]; short8 v; } cv;
      cv.u[0] = pack_bf16(__expf(x.x), __expf(x.y));
      cv.u[1] = pack_bf16(__expf(x.z), __expf(x.w));
      cv.u[2] = pack_bf16(__expf(y.x), __expf(y.y));
      cv.u[3] = pack_bf16(__expf(y.z), __expf(y.w));
      af[c] = cv.v;
    }
  }

  // Emit pointer: lane's 4 C-entries = rows w*16+4q+[0..4), col s.
  const float* fp = feats + (size_t)seq * (Lsz * Tsz) + w * 16 + 4 * q;

  // 4-deep static ring: slot k holds emit row (t with t%4==k), clamped to lim
  float4 pa0, pa1, pa2, pa3;
  { int r1 = (1 < lim) ? 1 : lim, r2 = (2 < lim) ? 2 : lim, r3 = (3 < lim) ? 3 : lim;
    if (lim < 1) r1 = r2 = r3 = lim;
    pa0 = *(const float4*)(fp);
    pa1 = *(const float4*)(fp + ((size_t)r1 << 7));
    pa2 = *(const float4*)(fp + ((size_t)r2 << 7));
    pa3 = *(const float4*)(fp + ((size_t)r3 << 7)); }

  float m_run = 0.0f, mcap = 0.0f;
  float ucap[4];
  #pragma unroll
  for (int i = 0; i < 4; ++i) ucap[i] = 1.0f;

// RS=1: rescale step (eta from u[0]+u[1], rcp, logf). RS=0: eta==1, all
// normalization ops elided (compile-time fold of the macro literal).
#define STEP(T, PA, BR, BW, RS)                                                \
  { const int t_ = (T);                                                        \
    float eex0 = __expf(PA.x), eex1 = __expf(PA.y);                            \
    float eex2 = __expf(PA.z), eex3 = __expf(PA.w);                            \
    short8 bq0 = *(const short8*)&u_lds[BR][s][0 * 32 + q * 8];                \
    short8 bq1 = *(const short8*)&u_lds[BR][s][1 * 32 + q * 8];                \
    short8 bq2 = *(const short8*)&u_lds[BR][s][2 * 32 + q * 8];                \
    short8 bq3 = *(const short8*)&u_lds[BR][s][3 * 32 + q * 8];                \
    unsigned ud = 0;                                                           \
    if (RS) ud = *(const unsigned*)&u_lds[BR][s][0];                           \
    int tp = t_ + 4; tp = (tp < lim) ? tp : lim;                               \
    PA = *(const float4*)(fp + ((size_t)tp << 7));                             \
    f32x4 z = {0.f, 0.f, 0.f, 0.f};                                            \
    f32x4 accA = __builtin_amdgcn_mfma_f32_16x16x32_bf16(af[0], bq0, z, 0,0,0);\
    f32x4 accB = __builtin_amdgcn_mfma_f32_16x16x32_bf16(af[2], bq2, z, 0,0,0);\
    accA = __builtin_amdgcn_mfma_f32_16x16x32_bf16(af[1], bq1, accA, 0,0,0);   \
    accB = __builtin_amdgcn_mfma_f32_16x16x32_bf16(af[3], bq3, accB, 0,0,0);   \
    float eta = 1.0f, rce = 1.0f;                                              \
    if (RS) {                                                                  \
      eta = bf16lo(ud) + bf16hi(ud);                                           \
      if (t_ == 0) eta = 1.0f;                                                 \
      rce = __builtin_amdgcn_rcpf(eta);                                        \
    }                                                                          \
    float uv[4];                                                               \
    if (RS) {                                                                  \
      uv[0] = (accA[0] + accB[0]) * rce * eex0;                                \
      uv[1] = (accA[1] + accB[1]) * rce * eex1;                                \
      uv[2] = (accA[2] + accB[2]) * rce * eex2;                                \
      uv[3] = (accA[3] + accB[3]) * rce * eex3;                                \
    } else {                                                                   \
      uv[0] = (accA[0] + accB[0]) * eex0;                                      \
      uv[1] = (accA[1] + accB[1]) * eex1;                                      \
      uv[2] = (accA[2] + accB[2]) * eex2;                                      \
      uv[3] = (accA[3] + accB[3]) * eex3;                                      \
    }                                                                          \
    unsigned short* dst = &u_lds[BW][s][0];                                    \
    uint2 pk; pk.x = cvt_pk_bf16(uv[0], uv[1]); pk.y = cvt_pk_bf16(uv[2], uv[3]); \
    *(uint2*)&dst[w * 16 + 4 * q] = pk;                                        \
    lds_barrier();                                                             \
    bool capt = (t_ == lim);                                                   \
    _Pragma("unroll") for (int i = 0; i < 4; ++i)                              \
      ucap[i] = capt ? uv[i] : ucap[i];                                        \
    if (RS) m_run += __logf(eta);                                              \
    mcap = capt ? m_run : mcap;                                                \
  }

  for (int t = 0; t < maxlen; t += 4) {
    STEP(t + 0, pa0, 0, 1, 1)
    STEP(t + 1, pa1, 1, 0, 0)
    STEP(t + 2, pa2, 0, 1, 0)
    STEP(t + 3, pa3, 1, 0, 0)
  }
#undef STEP

  __syncthreads();

  // Terminal fv: each wave computes its own 4 rows, stages to LDS; waves 0-3
  // then replay the exact verified reduction tree.
  #pragma unroll
  for (int r = 0; r < 4; ++r) {
    int row = w * 16 + 4 * q + r;
    fv_sh[row][s] = __logf(ucap[r]) + mcap + trans[TAG_START * Tsz + row];
  }
  __syncthreads();

  float fwd_score = 0.f;
  float fvv[8];
  if (w < 4) {
    #pragma unroll
    for (int i = 0; i < 2; ++i)
      #pragma unroll
      for (int r = 0; r < 4; ++r)
        fvv[i * 4 + r] = fv_sh[(2 * w + i) * 16 + 4 * q + r][s];
    float mx = fvv[0];
    #pragma unroll
    for (int i = 1; i < 8; ++i) mx = fmaxf(mx, fvv[i]);
    mx = fmaxf(mx, __shfl_xor(mx, 16, 64));
    mx = fmaxf(mx, __shfl_xor(mx, 32, 64));
    if (q == 0) red[w][s] = mx;
  }
  __syncthreads();
  float gmx = 0.f;
  if (w < 4) gmx = fmaxf(fmaxf(red[0][s], red[1][s]), fmaxf(red[2][s], red[3][s]));
  __syncthreads();
  if (w < 4) {
    float se = 0.f;
    #pragma unroll
    for (int i = 0; i < 8; ++i) se += __expf(fvv[i] - gmx);
    se += __shfl_xor(se, 16, 64);
    se += __shfl_xor(se, 32, 64);
    if (q == 0) red[w][s] = se;
  }
  __syncthreads();
  if (w < 4)
    fwd_score = gmx + __logf((red[0][s] + red[1][s]) + (red[2][s] + red[3][s]));

  // ---- gold score: waves 0-3 exactly as before (seq 4w+q; 16 lanes per seq) ----
  if (w < 4) {
    int jj = 4 * w + q;
    int gs2 = g * SPB + jj;
    int lenj = lens[gs2];
    const int* tg = tags + (size_t)gs2 * Lsz;
    const float* fbj = feats + (size_t)gs2 * (Lsz * Tsz);
    float acc = 0.f;
    for (int pos = s; pos <= lenj; pos += 16) {
      int st = (pos == 0)    ? TAG_START : tg[pos - 1];
      int et = (pos == lenj) ? TAG_STOP  : tg[pos];
      acc += trans[et * Tsz + st];
    }
    for (int l = s; l < lenj; l += 16)
      acc += fbj[(size_t)l * Tsz + tg[l]];
    #pragma unroll
    for (int off = 1; off < 16; off <<= 1) acc += __shfl_xor(acc, off, 64);
    if (s == 0) gold_sh[jj] = acc;
  }
  __syncthreads();
  if (w == 0 && q == 0)
    diff_out[g * SPB + s] = fwd_score - gold_sh[s];
}

// loss = mean(diff)
__global__ __launch_bounds__(Bsz) void crf_final_kernel(
    const float* __restrict__ diff, float* __restrict__ out)
{
  int tid = threadIdx.x;
  float v = diff[tid];
  __shared__ float wred[8];
  float sum = v;
  #pragma unroll
  for (int off = 32; off > 0; off >>= 1) sum += __shfl_down(sum, off, 64);
  int wave = tid >> 6, lane = tid & 63;
  if (lane == 0) wred[wave] = sum;
  __syncthreads();
  if (tid == 0) {
    float t = 0.f;
    #pragma unroll
    for (int i = 0; i < 8; ++i) t += wred[i];
    out[0] = t * (1.0f / Bsz);
  }
}

extern "C" void kernel_launch(void* const* d_in, const int* in_sizes, int n_in,
                              void* d_out, int out_size, void* d_ws, size_t ws_size,
                              hipStream_t stream) {
  const float* feats = (const float*)d_in[0];
  const float* trans = (const float*)d_in[1];
  const int*   tags  = (const int*)d_in[2];
  const int*   lens  = (const int*)d_in[3];
  float* out  = (float*)d_out;
  float* diff = (float*)d_ws;

  crf_fwd_kernel<<<Bsz / SPB, 512, 0, stream>>>(feats, trans, tags, lens, diff);
  crf_final_kernel<<<1, Bsz, 0, stream>>>(diff, out);
}